// Round 5
// baseline (1071.510 us; speedup 1.0000x reference)
//
#include <hip/hip_runtime.h>
#include <hip/hip_bf16.h>

#define IN_F 128
#define HF 256
#define BN_EPS 1e-5f
#define SELU_SCALE 1.0507009873554805f
#define SELU_ALPHA 1.6732632423543772f
#define GRID_P 256

typedef __attribute__((ext_vector_type(8))) _Float16 half8;
typedef __attribute__((ext_vector_type(4))) short short4v;
typedef __attribute__((ext_vector_type(4))) float f32x4;

__device__ __forceinline__ short f2h(float f) {
    _Float16 h = (_Float16)f;               // RTNE fp32->fp16
    return __builtin_bit_cast(short, h);
}

__device__ __forceinline__ float selu_f(float x) {
    return SELU_SCALE * (x > 0.f ? x : SELU_ALPHA * expm1f(x));
}

// async global->LDS, 16B per lane; LDS dest = wave-uniform base + lane*16
__device__ __forceinline__ void gld_lds16(const void* g, void* l) {
    __builtin_amdgcn_global_load_lds(
        (const __attribute__((address_space(1))) unsigned int*)g,
        (__attribute__((address_space(3))) unsigned int*)l, 16, 0, 0);
}

// x fp32 -> fp16 (plain layout), parked in the agg region of d_out (dead until GEMM1 done)
__global__ void cvt_x_kernel(const float* __restrict__ x, unsigned short* __restrict__ x16, int n4) {
    int i = blockIdx.x * 256 + threadIdx.x;
    if (i < n4) {
        f32x4 v = ((const f32x4*)x)[i];
        short4v p;
        p[0] = f2h(v[0]); p[1] = f2h(v[1]); p[2] = f2h(v[2]); p[3] = f2h(v[3]);
        ((short4v*)x16)[i] = p;
    }
}

// Fold BN into weights; store fp16 PLAIN row-major [n][k] (B is consumed into
// registers now, no LDS banking concern).
__global__ void prep_kernel(const float* __restrict__ W0, const float* __restrict__ b0,
                            const float* __restrict__ g0, const float* __restrict__ beta0,
                            const float* __restrict__ m0, const float* __restrict__ v0,
                            const float* __restrict__ Ws, const float* __restrict__ bs,
                            const float* __restrict__ gs, const float* __restrict__ betas,
                            const float* __restrict__ ms, const float* __restrict__ vs,
                            unsigned short* __restrict__ Wh, float* __restrict__ biasArr) {
    int b = blockIdx.x;
    int layer = b >> 8;
    int n = b & 255;
    int k = threadIdx.x;
    const float *W, *bb, *g, *be, *m, *v;
    if (layer == 0) { W = W0; bb = b0; g = g0; be = beta0; m = m0; v = v0; }
    else {
        int i = layer - 1;
        W = Ws + (size_t)i * HF * HF; bb = bs + i * HF; g = gs + i * HF;
        be = betas + i * HF; m = ms + i * HF; v = vs + i * HF;
    }
    float s = g[n] * rsqrtf(v[n] + BN_EPS);
    Wh[(size_t)layer * HF * HF + n * HF + k] = (unsigned short)f2h(W[n * HF + k] * s);
    if (k == 0) biasArr[layer * HF + n] = (bb[n] - m[n]) * s + be[n];
}

__global__ void count_kernel(const int* __restrict__ dstI, int* __restrict__ cnt, int E) {
    int i = blockIdx.x * 256 + threadIdx.x;
    if (i < E) atomicAdd(cnt + dstI[i], 1);
}

__global__ void finalize_kernel(float* __restrict__ agg, const int* __restrict__ cnt) {
    int n = blockIdx.x;
    float c = fmaxf((float)cnt[n], 1.f);
    agg[(size_t)n * HF + threadIdx.x] = agg[(size_t)n * HF + threadIdx.x] / c;
}

// Persistent GEMM: 256 blocks x 512 thr (8 waves, 2 row-halves x 4 col-slabs).
// Each wave holds its full B slab (64 cols x 256 K fp16) in 128 VGPRs, loaded
// once. Blocks loop over 128-edge tiles; A double-buffered in LDS (2x16KB),
// next stage issued before MFMA (m97 2-phase). Epilogue staged in LDS @+32KB.
// MODE 0: A = gather-concat x16 (XOR-swizzle folded into gather addr) -> hh fp16
// MODE 1: A = hh -> hh (in-place, low 512B of each 1KB slot)
// MODE 2: A = hh -> final h fp32 full rows + atomic scatter into agg
template <int MODE>
__global__ __launch_bounds__(512, 2)
void gemm_kernel(const unsigned short* __restrict__ x16,
                 const unsigned char* __restrict__ hhB,
                 const int* __restrict__ dstI, const int* __restrict__ srcI,
                 const unsigned short* __restrict__ Wh,   // this layer, plain [n][k]
                 const float* __restrict__ biasArr,       // this layer
                 unsigned char* __restrict__ outB,
                 float* __restrict__ agg, int NT) {
    __shared__ __align__(16) unsigned char lds[65536];   // A: 2x16KB | epilogue: 32KB @ +32768

    const int t = threadIdx.x;
    const int lane = t & 63;
    const int w = t >> 6;           // 0..7
    const int wr = w >> 2;          // 0..1 : 64-row half
    const int wcol = w & 3;         // 0..3 : 64-col slab
    const int lrow = lane & 15;
    const int lgrp = lane >> 4;
    const int lko = lgrp * 8;       // k offset (halfs) within 32-wide slice
    const int sub = lane & 7;       // 16B chunk within 128B row-segment
    const int r8 = lane >> 3;       // row within 8-row staging chunk
    unsigned char* EP = lds + 32768;

    // ---- B slab -> registers (once per block) ----
    half8 breg[4][8];
#pragma unroll
    for (int ni = 0; ni < 4; ++ni)
#pragma unroll
        for (int s = 0; s < 8; ++s)
            breg[ni][s] = *(const half8*)(Wh + (size_t)(wcol * 64 + ni * 16 + lrow) * HF + s * 32 + lko);

    // stage one 64-k slice of A (16KB) into buf; 2 chunks of 8 rows per wave
    auto stage = [&](int base, int kk, unsigned char* buf, int d0, int d1, int s0, int s1) {
#pragma unroll
        for (int i = 0; i < 2; ++i) {
            int c = w * 2 + i;
            int row = c * 8 + r8;
            const unsigned char* g;
            if (MODE == 0) {
                int idx = (kk < 2) ? (i ? d1 : d0) : (i ? s1 : s0);
                g = (const unsigned char*)x16 + (size_t)idx * 256 + (kk & 1) * 128
                    + ((sub * 16) ^ (r8 << 4));
            } else {
                g = hhB + (size_t)(base + row) * 1024 + kk * 128 + sub * 16;
            }
            gld_lds16(g, buf + c * 1024);
        }
    };

    // ---- prologue: indices + first stage for tile blockIdx.x ----
    int cd0 = 0, cd1 = 0, cs0 = 0, cs1 = 0;
    {
        int b0r = blockIdx.x * 128;
        if (MODE == 0) {
            cd0 = dstI[b0r + (w * 2) * 8 + r8];
            cd1 = dstI[b0r + (w * 2 + 1) * 8 + r8];
            cs0 = srcI[b0r + (w * 2) * 8 + r8];
            cs1 = srcI[b0r + (w * 2 + 1) * 8 + r8];
        }
        stage(b0r, 0, lds, cd0, cd1, cs0, cs1);
    }
    __syncthreads();

    for (int tile = blockIdx.x; tile < NT; tile += GRID_P) {
        const int base = tile * 128;
        const int ntile = tile + GRID_P;
        int nd0 = 0, nd1 = 0, ns0 = 0, ns1 = 0;
        if (MODE == 0 && ntile < NT) {            // prefetch next tile's gather indices
            int nb = ntile * 128;
            nd0 = dstI[nb + (w * 2) * 8 + r8];
            nd1 = dstI[nb + (w * 2 + 1) * 8 + r8];
            ns0 = srcI[nb + (w * 2) * 8 + r8];
            ns1 = srcI[nb + (w * 2 + 1) * 8 + r8];
        }

        f32x4 acc[4][4];
        const f32x4 zero = {0.f, 0.f, 0.f, 0.f};
#pragma unroll
        for (int mi = 0; mi < 4; ++mi)
#pragma unroll
            for (int ni = 0; ni < 4; ++ni) acc[mi][ni] = zero;

#pragma unroll
        for (int kk = 0; kk < 4; ++kk) {
            unsigned char* cur = lds + (kk & 1) * 16384;
            unsigned char* nxt = lds + ((kk + 1) & 1) * 16384;
            if (kk < 3)
                stage(base, kk + 1, nxt, cd0, cd1, cs0, cs1);
            else if (ntile < NT)
                stage(ntile * 128, 0, nxt, nd0, nd1, ns0, ns1);
#pragma unroll
            for (int kI = 0; kI < 2; ++kI) {
                half8 a[4];
#pragma unroll
                for (int mi = 0; mi < 4; ++mi) {
                    int r = wr * 64 + mi * 16 + lrow;
                    a[mi] = *(const half8*)&cur[r * 128 + (((kI * 32 + lko) * 2) ^ ((r & 7) << 4))];
                }
#pragma unroll
                for (int mi = 0; mi < 4; ++mi)
#pragma unroll
                    for (int ni = 0; ni < 4; ++ni)
                        acc[mi][ni] = __builtin_amdgcn_mfma_f32_16x16x32_f16(
                            a[mi], breg[ni][kk * 2 + kI], acc[mi][ni], 0, 0, 0);
            }
            __syncthreads();
        }

        float bc[4];
#pragma unroll
        for (int ni = 0; ni < 4; ++ni) bc[ni] = biasArr[wcol * 64 + ni * 16 + lrow];

        if (MODE < 2) {
            // fp16 swizzled out: 2 chunks of 64 rows (32KB EP stage)
#pragma unroll
            for (int cc = 0; cc < 2; ++cc) {
                if (cc) __syncthreads();
                if (wr == cc) {
#pragma unroll
                    for (int mi = 0; mi < 4; ++mi)
#pragma unroll
                        for (int ni = 0; ni < 4; ++ni)
#pragma unroll
                            for (int r = 0; r < 4; ++r) {
                                int lr = mi * 16 + lgrp * 4 + r;          // 0..63
                                int cg = wcol * 64 + ni * 16 + lrow;      // 0..255
                                float val = selu_f(acc[mi][ni][r] + bc[ni]);
                                int pos = (cg >> 6) * 128 + (((cg & 63) * 2) ^ ((lr & 7) << 4));
                                *(short*)&EP[lr * 512 + pos] = f2h(val);
                            }
                }
                __syncthreads();
#pragma unroll
                for (int i = 0; i < 4; ++i) {
                    int f = t + i * 512;                  // 2048 x 16B = 64 rows x 32
                    int row = f >> 5, ch = f & 31;
                    int e = base + cc * 64 + row;
                    f32x4 v = *(const f32x4*)&EP[row * 512 + ch * 16];
                    *(f32x4*)(outB + (size_t)e * 1024 + ch * 16) = v;
                }
            }
        } else {
            // fp32 plain out: 4 chunks of 32 rows (32KB EP stage) + atomics
#pragma unroll
            for (int cc = 0; cc < 4; ++cc) {
                if (cc) __syncthreads();
                if (wr == (cc >> 1)) {
#pragma unroll
                    for (int m2 = 0; m2 < 2; ++m2) {
                        int mi = (cc & 1) * 2 + m2;
#pragma unroll
                        for (int ni = 0; ni < 4; ++ni)
#pragma unroll
                            for (int r = 0; r < 4; ++r) {
                                int lr = m2 * 16 + lgrp * 4 + r;          // 0..31
                                int cg = wcol * 64 + ni * 16 + lrow;
                                float val = selu_f(acc[mi][ni][r] + bc[ni]);
                                *(float*)&EP[lr * 1024 + cg * 4] = val;
                                int e = base + cc * 32 + lr;
                                atomicAdd(agg + (size_t)dstI[e] * HF + cg, val);
                            }
                    }
                }
                __syncthreads();
#pragma unroll
                for (int i = 0; i < 4; ++i) {
                    int f = t + i * 512;                  // 2048 x 16B = 32 rows x 64
                    int row = f >> 6, ch = f & 63;
                    int e = base + cc * 32 + row;
                    f32x4 v = *(const f32x4*)&EP[row * 1024 + ch * 16];
                    *(f32x4*)(outB + (size_t)e * 1024 + ch * 16) = v;
                }
            }
        }
        __syncthreads();   // EP reads done before next tile's epilogue rewrites

        cd0 = nd0; cd1 = nd1; cs0 = ns0; cs1 = ns1;
    }
}

extern "C" void kernel_launch(void* const* d_in, const int* in_sizes, int n_in,
                              void* d_out, int out_size, void* d_ws, size_t ws_size,
                              hipStream_t stream) {
    const float* x     = (const float*)d_in[0];
    const int*   ei    = (const int*)d_in[1];
    const float* W0    = (const float*)d_in[2];
    const float* b0    = (const float*)d_in[3];
    const float* g0    = (const float*)d_in[4];
    const float* beta0 = (const float*)d_in[5];
    const float* m0    = (const float*)d_in[6];
    const float* v0    = (const float*)d_in[7];
    const float* Ws    = (const float*)d_in[8];
    const float* bs    = (const float*)d_in[9];
    const float* gs    = (const float*)d_in[10];
    const float* betas = (const float*)d_in[11];
    const float* ms    = (const float*)d_in[12];
    const float* vs    = (const float*)d_in[13];

    const int Nn = in_sizes[0] / IN_F;   // 20000
    const int E  = in_sizes[1] / 2;      // 320000
    const int NT = E / 128;              // 2500 tiles

    float* agg  = (float*)d_out;
    float* hptr = agg + (size_t)Nn * HF;             // h region: E slots of 1KB
    unsigned char* hhB = (unsigned char*)hptr;       // fp16 intermediates in low 512B of each slot

    // ws: Wh (384KB plain fp16) | biasArr (3KB) | cnt (80KB)
    unsigned short* Wh = (unsigned short*)d_ws;
    float* biasArr = (float*)((char*)d_ws + 3 * HF * HF * sizeof(unsigned short));
    int* cnt = (int*)((char*)d_ws + 3 * HF * HF * sizeof(unsigned short) + 3 * HF * sizeof(float));

    const int* srcI = ei;        // edge_index[0]
    const int* dstI = ei + E;    // edge_index[1]

    // x16 (5.12MB) parked in the agg region (dead until after GEMM1)
    unsigned short* x16 = (unsigned short*)d_out;

    cvt_x_kernel<<<(Nn * IN_F / 4 + 255) / 256, 256, 0, stream>>>(x, x16, Nn * IN_F / 4);
    prep_kernel<<<3 * HF, HF, 0, stream>>>(W0, b0, g0, beta0, m0, v0,
                                           Ws, bs, gs, betas, ms, vs, Wh, biasArr);
    hipMemsetAsync(cnt, 0, (size_t)Nn * sizeof(int), stream);
    count_kernel<<<(E + 255) / 256, 256, 0, stream>>>(dstI, cnt, E);

    gemm_kernel<0><<<GRID_P, 512, 0, stream>>>(x16, hhB, dstI, srcI,
                                               Wh, biasArr, hhB, nullptr, NT);
    hipMemsetAsync(agg, 0, (size_t)Nn * HF * sizeof(float), stream);   // x16 dead now
    gemm_kernel<1><<<GRID_P, 512, 0, stream>>>(x16, hhB, dstI, srcI,
                                               Wh + HF * HF, biasArr + HF, hhB, nullptr, NT);
    gemm_kernel<2><<<GRID_P, 512, 0, stream>>>(x16, hhB, dstI, srcI,
                                               Wh + 2 * HF * HF, biasArr + 2 * HF,
                                               (unsigned char*)hptr, agg, NT);

    finalize_kernel<<<Nn, HF, 0, stream>>>(agg, cnt);
}

// Round 6
// 853.810 us; speedup vs baseline: 1.2550x; 1.2550x over previous
//
#include <hip/hip_runtime.h>
#include <hip/hip_bf16.h>

#define IN_F 128
#define HF 256
#define BN_EPS 1e-5f
#define SELU_SCALE 1.0507009873554805f
#define SELU_ALPHA 1.6732632423543772f

typedef __attribute__((ext_vector_type(8))) _Float16 half8;
typedef __attribute__((ext_vector_type(4))) short short4v;
typedef __attribute__((ext_vector_type(4))) float f32x4;

__device__ __forceinline__ short f2h(float f) {
    _Float16 h = (_Float16)f;               // RTNE fp32->fp16
    return __builtin_bit_cast(short, h);
}

__device__ __forceinline__ float selu_f(float x) {
    return SELU_SCALE * (x > 0.f ? x : SELU_ALPHA * expm1f(x));
}

// async global->LDS, 16B per lane; LDS dest = wave-uniform base + lane*16
__device__ __forceinline__ void gld_lds16(const void* g, void* l) {
    __builtin_amdgcn_global_load_lds(
        (const __attribute__((address_space(1))) unsigned int*)g,
        (__attribute__((address_space(3))) unsigned int*)l, 16, 0, 0);
}

// x fp32 -> fp16 (plain layout), parked in the agg region of d_out (dead until GEMM1 done)
__global__ void cvt_x_kernel(const float* __restrict__ x, unsigned short* __restrict__ x16, int n4) {
    int i = blockIdx.x * 256 + threadIdx.x;
    if (i < n4) {
        f32x4 v = ((const f32x4*)x)[i];
        short4v p;
        p[0] = f2h(v[0]); p[1] = f2h(v[1]); p[2] = f2h(v[2]); p[3] = f2h(v[3]);
        ((short4v*)x16)[i] = p;
    }
}

// Fold BN into weights; store fp16 PLAIN row-major [n][k] (B goes to registers).
__global__ void prep_kernel(const float* __restrict__ W0, const float* __restrict__ b0,
                            const float* __restrict__ g0, const float* __restrict__ beta0,
                            const float* __restrict__ m0, const float* __restrict__ v0,
                            const float* __restrict__ Ws, const float* __restrict__ bs,
                            const float* __restrict__ gs, const float* __restrict__ betas,
                            const float* __restrict__ ms, const float* __restrict__ vs,
                            unsigned short* __restrict__ Wh, float* __restrict__ biasArr) {
    int b = blockIdx.x;
    int layer = b >> 8;
    int n = b & 255;
    int k = threadIdx.x;
    const float *W, *bb, *g, *be, *m, *v;
    if (layer == 0) { W = W0; bb = b0; g = g0; be = beta0; m = m0; v = v0; }
    else {
        int i = layer - 1;
        W = Ws + (size_t)i * HF * HF; bb = bs + i * HF; g = gs + i * HF;
        be = betas + i * HF; m = ms + i * HF; v = vs + i * HF;
    }
    float s = g[n] * rsqrtf(v[n] + BN_EPS);
    Wh[(size_t)layer * HF * HF + n * HF + k] = (unsigned short)f2h(W[n * HF + k] * s);
    if (k == 0) biasArr[layer * HF + n] = (bb[n] - m[n]) * s + be[n];
}

__global__ void count_kernel(const int* __restrict__ dstI, int* __restrict__ cnt, int E) {
    int i = blockIdx.x * 256 + threadIdx.x;
    if (i < E) atomicAdd(cnt + dstI[i], 1);
}

__global__ void finalize_kernel(float* __restrict__ agg, const int* __restrict__ cnt) {
    int n = blockIdx.x;
    float c = fmaxf((float)cnt[n], 1.f);
    agg[(size_t)n * HF + threadIdx.x] = agg[(size_t)n * HF + threadIdx.x] / c;
}

// One block = 128 edges x all 256 cols. 512 thr = 8 waves (2 row-halves x 4 col
// slabs); wave tile 64x64 via 4x4 frags of mfma_f32_16x16x32_f16.
// B slab (64 cols x K=256) lives in 128 VGPRs, loaded once from L2.
// Whole A tile (128 x 512B fp16) staged in ONE shot via 8 global_load_lds/wave
// -> 1 barrier -> 128 MFMAs/wave with no barrier inside. Epilogue reuses LDS.
// hh rows are fp16, 4x128B segments, XOR-swizzled within segment: stored byte
//   seg*128 + ((b&127) ^ ((row&7)<<4))   -> ds_read_b128 conflict-free.
// MODE 0: A = gather-concat x16 (swizzle folded into gather addr) -> hh fp16
// MODE 1: A = hh -> hh (in-place, low 512B of each 1KB slot)
// MODE 2: A = hh -> final h fp32 full rows + atomic scatter into agg
template <int MODE>
__global__ __launch_bounds__(512)
void gemm_kernel(const unsigned short* __restrict__ x16,
                 const unsigned char* __restrict__ hhB,
                 const int* __restrict__ dstI, const int* __restrict__ srcI,
                 const unsigned short* __restrict__ Wh,   // this layer, plain [n][k]
                 const float* __restrict__ biasArr,       // this layer
                 unsigned char* __restrict__ outB,
                 float* __restrict__ agg) {
    __shared__ __align__(16) unsigned char lds[65536];

    const int base = blockIdx.x * 128;
    const int t = threadIdx.x;
    const int lane = t & 63;
    const int w = t >> 6;           // 0..7
    const int wr = w >> 2;          // 0..1 : 64-row half
    const int wcol = w & 3;         // 0..3 : 64-col slab
    const int lrow = lane & 15;
    const int lgrp = lane >> 4;
    const int lko = lgrp * 8;       // k offset (halfs) within 32-wide slice
    const int rsel = lane >> 5;     // row parity within 1KB chunk (2 rows/chunk)
    const int bIn = (lane & 31) * 16;   // byte within 512B row
    const int seg = bIn >> 7;           // 128B segment 0..3

    // ---- stage whole A tile: 64 chunks of 1KB, 8 per wave ----
#pragma unroll
    for (int i = 0; i < 8; ++i) {
        int c = w * 8 + i;              // chunk 0..63
        int row = c * 2 + rsel;         // tile row 0..127
        const unsigned char* g;
        if (MODE == 0) {
            int e = base + row;
            int idx = (seg < 2 ? dstI : srcI)[e];
            g = (const unsigned char*)x16 + (size_t)idx * 256 + (seg & 1) * 128
                + ((bIn & 127) ^ ((row & 7) << 4));   // pre-swizzled gather
        } else {
            g = hhB + (size_t)(base + row) * 1024 + bIn;   // already swizzled
        }
        gld_lds16(g, lds + c * 1024);
    }

    // ---- B slab -> registers (once) ----
    half8 breg[4][8];
#pragma unroll
    for (int ni = 0; ni < 4; ++ni)
#pragma unroll
        for (int s = 0; s < 8; ++s)
            breg[ni][s] = *(const half8*)(Wh + (size_t)(wcol * 64 + ni * 16 + lrow) * HF + s * 32 + lko);

    __syncthreads();

    // ---- K loop: 8 slices of 32, no barriers ----
    f32x4 acc[4][4];
    const f32x4 zero = {0.f, 0.f, 0.f, 0.f};
#pragma unroll
    for (int mi = 0; mi < 4; ++mi)
#pragma unroll
        for (int ni = 0; ni < 4; ++ni) acc[mi][ni] = zero;

#pragma unroll
    for (int s = 0; s < 8; ++s) {
        half8 a[4];
#pragma unroll
        for (int mi = 0; mi < 4; ++mi) {
            int r = wr * 64 + mi * 16 + lrow;
            a[mi] = *(const half8*)&lds[r * 512 + ((s * 64 + lgrp * 16) ^ ((r & 7) << 4))];
        }
#pragma unroll
        for (int mi = 0; mi < 4; ++mi)
#pragma unroll
            for (int ni = 0; ni < 4; ++ni)
                acc[mi][ni] = __builtin_amdgcn_mfma_f32_16x16x32_f16(
                    a[mi], breg[ni][s], acc[mi][ni], 0, 0, 0);
    }
    __syncthreads();        // all ds_reads done before epilogue overwrites LDS

    float bc[4];
#pragma unroll
    for (int ni = 0; ni < 4; ++ni) bc[ni] = biasArr[wcol * 64 + ni * 16 + lrow];

    if (MODE < 2) {
        // ---- fp16 swizzled epilogue: all 128 rows into the 64KB at once ----
#pragma unroll
        for (int mi = 0; mi < 4; ++mi)
#pragma unroll
            for (int ni = 0; ni < 4; ++ni)
#pragma unroll
                for (int r = 0; r < 4; ++r) {
                    int lr = wr * 64 + mi * 16 + lgrp * 4 + r;     // 0..127
                    int cg = wcol * 64 + ni * 16 + lrow;           // 0..255
                    float val = selu_f(acc[mi][ni][r] + bc[ni]);
                    int pos = (cg >> 6) * 128 + (((cg & 63) * 2) ^ ((lr & 7) << 4));
                    *(short*)&lds[lr * 512 + pos] = f2h(val);
                }
        __syncthreads();
#pragma unroll
        for (int i = 0; i < 8; ++i) {
            int f = t + i * 512;                 // 4096 x 16B = 128 rows x 32
            int row = f >> 5, ch = f & 31;
            int e = base + row;
            f32x4 v = *(const f32x4*)&lds[row * 512 + ch * 16];
            *(f32x4*)(outB + (size_t)e * 1024 + ch * 16) = v;
        }
    } else {
        // ---- fp32 epilogue: 2 passes of 64 rows (64KB) + atomic scatter ----
#pragma unroll
        for (int pass = 0; pass < 2; ++pass) {
            if (pass) __syncthreads();
            if (wr == pass) {
#pragma unroll
                for (int mi = 0; mi < 4; ++mi)
#pragma unroll
                    for (int ni = 0; ni < 4; ++ni)
#pragma unroll
                        for (int r = 0; r < 4; ++r) {
                            int lr = mi * 16 + lgrp * 4 + r;       // 0..63
                            int cg = wcol * 64 + ni * 16 + lrow;
                            float val = selu_f(acc[mi][ni][r] + bc[ni]);
                            *(float*)&lds[lr * 1024 + cg * 4] = val;
                            int e = base + pass * 64 + lr;
                            atomicAdd(agg + (size_t)dstI[e] * HF + cg, val);
                        }
            }
            __syncthreads();
#pragma unroll
            for (int i = 0; i < 8; ++i) {
                int f = t + i * 512;             // 4096 x 16B = 64 rows x 64
                int row = f >> 6, ch = f & 63;
                int e = base + pass * 64 + row;
                f32x4 v = *(const f32x4*)&lds[row * 1024 + ch * 16];
                *(f32x4*)(outB + (size_t)e * 1024 + ch * 16) = v;
            }
        }
    }
}

extern "C" void kernel_launch(void* const* d_in, const int* in_sizes, int n_in,
                              void* d_out, int out_size, void* d_ws, size_t ws_size,
                              hipStream_t stream) {
    const float* x     = (const float*)d_in[0];
    const int*   ei    = (const int*)d_in[1];
    const float* W0    = (const float*)d_in[2];
    const float* b0    = (const float*)d_in[3];
    const float* g0    = (const float*)d_in[4];
    const float* beta0 = (const float*)d_in[5];
    const float* m0    = (const float*)d_in[6];
    const float* v0    = (const float*)d_in[7];
    const float* Ws    = (const float*)d_in[8];
    const float* bs    = (const float*)d_in[9];
    const float* gs    = (const float*)d_in[10];
    const float* betas = (const float*)d_in[11];
    const float* ms    = (const float*)d_in[12];
    const float* vs    = (const float*)d_in[13];

    const int Nn = in_sizes[0] / IN_F;   // 20000
    const int E  = in_sizes[1] / 2;      // 320000

    float* agg  = (float*)d_out;
    float* hptr = agg + (size_t)Nn * HF;             // h region: E slots of 1KB
    unsigned char* hhB = (unsigned char*)hptr;       // fp16 intermediates in low 512B of each slot

    // ws: Wh (384KB plain fp16) | biasArr (3KB) | cnt (80KB)
    unsigned short* Wh = (unsigned short*)d_ws;
    float* biasArr = (float*)((char*)d_ws + 3 * HF * HF * sizeof(unsigned short));
    int* cnt = (int*)((char*)d_ws + 3 * HF * HF * sizeof(unsigned short) + 3 * HF * sizeof(float));

    const int* srcI = ei;        // edge_index[0]
    const int* dstI = ei + E;    // edge_index[1]

    // x16 (10.24MB fp16) parked in the agg region (dead until after GEMM1)
    unsigned short* x16 = (unsigned short*)d_out;

    cvt_x_kernel<<<(Nn * IN_F / 4 + 255) / 256, 256, 0, stream>>>(x, x16, Nn * IN_F / 4);
    prep_kernel<<<3 * HF, HF, 0, stream>>>(W0, b0, g0, beta0, m0, v0,
                                           Ws, bs, gs, betas, ms, vs, Wh, biasArr);
    hipMemsetAsync(cnt, 0, (size_t)Nn * sizeof(int), stream);
    count_kernel<<<(E + 255) / 256, 256, 0, stream>>>(dstI, cnt, E);

    gemm_kernel<0><<<E / 128, 512, 0, stream>>>(x16, hhB, dstI, srcI,
                                                Wh, biasArr, hhB, nullptr);
    hipMemsetAsync(agg, 0, (size_t)Nn * HF * sizeof(float), stream);   // x16 dead now
    gemm_kernel<1><<<E / 128, 512, 0, stream>>>(x16, hhB, dstI, srcI,
                                                Wh + HF * HF, biasArr + HF, hhB, nullptr);
    gemm_kernel<2><<<E / 128, 512, 0, stream>>>(x16, hhB, dstI, srcI,
                                                Wh + 2 * HF * HF, biasArr + 2 * HF,
                                                (unsigned char*)hptr, agg);

    finalize_kernel<<<Nn, HF, 0, stream>>>(agg, cnt);
}

// Round 7
// 848.672 us; speedup vs baseline: 1.2626x; 1.0061x over previous
//
#include <hip/hip_runtime.h>
#include <hip/hip_bf16.h>

#define IN_F 128
#define HF 256
#define BN_EPS 1e-5f
#define SELU_SCALE 1.0507009873554805f
#define SELU_ALPHA 1.6732632423543772f

typedef __attribute__((ext_vector_type(8))) _Float16 half8;
typedef __attribute__((ext_vector_type(4))) short short4v;
typedef __attribute__((ext_vector_type(4))) float f32x4;

__device__ __forceinline__ short f2h(float f) {
    _Float16 h = (_Float16)f;               // RTNE fp32->fp16
    return __builtin_bit_cast(short, h);
}

__device__ __forceinline__ float selu_f(float x) {
    return SELU_SCALE * (x > 0.f ? x : SELU_ALPHA * expm1f(x));
}

// async global->LDS, 16B per lane; LDS dest = wave-uniform base + lane*16
__device__ __forceinline__ void gld_lds16(const void* g, void* l) {
    __builtin_amdgcn_global_load_lds(
        (const __attribute__((address_space(1))) unsigned int*)g,
        (__attribute__((address_space(3))) unsigned int*)l, 16, 0, 0);
}

// x fp32 -> fp16 (plain layout), parked in the agg region of d_out (dead until GEMM1 done)
__global__ void cvt_x_kernel(const float* __restrict__ x, unsigned short* __restrict__ x16, int n4) {
    int i = blockIdx.x * 256 + threadIdx.x;
    if (i < n4) {
        f32x4 v = ((const f32x4*)x)[i];
        short4v p;
        p[0] = f2h(v[0]); p[1] = f2h(v[1]); p[2] = f2h(v[2]); p[3] = f2h(v[3]);
        ((short4v*)x16)[i] = p;
    }
}

// Fold BN into weights; store fp16 PLAIN row-major [n][k] (B frags loaded to VGPR).
__global__ void prep_kernel(const float* __restrict__ W0, const float* __restrict__ b0,
                            const float* __restrict__ g0, const float* __restrict__ beta0,
                            const float* __restrict__ m0, const float* __restrict__ v0,
                            const float* __restrict__ Ws, const float* __restrict__ bs,
                            const float* __restrict__ gs, const float* __restrict__ betas,
                            const float* __restrict__ ms, const float* __restrict__ vs,
                            unsigned short* __restrict__ Wh, float* __restrict__ biasArr) {
    int b = blockIdx.x;
    int layer = b >> 8;
    int n = b & 255;
    int k = threadIdx.x;
    const float *W, *bb, *g, *be, *m, *v;
    if (layer == 0) { W = W0; bb = b0; g = g0; be = beta0; m = m0; v = v0; }
    else {
        int i = layer - 1;
        W = Ws + (size_t)i * HF * HF; bb = bs + i * HF; g = gs + i * HF;
        be = betas + i * HF; m = ms + i * HF; v = vs + i * HF;
    }
    float s = g[n] * rsqrtf(v[n] + BN_EPS);
    Wh[(size_t)layer * HF * HF + n * HF + k] = (unsigned short)f2h(W[n * HF + k] * s);
    if (k == 0) biasArr[layer * HF + n] = (bb[n] - m[n]) * s + be[n];
}

__global__ void count_kernel(const int* __restrict__ dstI, int* __restrict__ cnt, int E) {
    int i = blockIdx.x * 256 + threadIdx.x;
    if (i < E) atomicAdd(cnt + dstI[i], 1);
}

__global__ void finalize_kernel(float* __restrict__ agg, const int* __restrict__ cnt) {
    int n = blockIdx.x;
    float c = fmaxf((float)cnt[n], 1.f);
    agg[(size_t)n * HF + threadIdx.x] = agg[(size_t)n * HF + threadIdx.x] / c;
}

// One block = 128 edges x all 256 cols. 512 thr = 8 waves (2 row-halves x 4 col
// slabs); wave tile 64x64 via 4x4 frags of mfma_f32_16x16x32_f16. BK=64, 4 steps.
// A double-buffered in LDS (2x16KB, 2-phase: stage k+1 issued before compute k,
// ONE barrier per step). B fragments loaded JIT from L2 (16B vector loads, not
// barrier-gated -> compiler pipelines them). Total LDS 32KB; epilogue reuses it.
// A-slice LDS: 128 rows x 128B, XOR-swizzled (byte ^ ((row&7)<<4)) -> 2-way max.
// hh rows: fp16, 4 x 128B segs, same per-seg swizzle, stored in low 512B of the
// edge's 1KB fp32 slot in d_out's h region.
// MODE 0: A = gather-concat x16 (swizzle folded into gather addr) -> hh fp16
// MODE 1: A = hh -> hh (in-place)
// MODE 2: A = hh -> final h fp32 full rows + atomic scatter into agg
template <int MODE>
__global__ __launch_bounds__(512)
void gemm_kernel(const unsigned short* __restrict__ x16,
                 const unsigned char* __restrict__ hhB,
                 const int* __restrict__ dstI, const int* __restrict__ srcI,
                 const unsigned short* __restrict__ Wh,   // this layer, plain [n][k]
                 const float* __restrict__ biasArr,       // this layer
                 unsigned char* __restrict__ outB,
                 float* __restrict__ agg) {
    __shared__ __align__(16) unsigned char lds[32768];   // A dbuf 2x16KB; epilogue reuse

    const int base = blockIdx.x * 128;
    const int t = threadIdx.x;
    const int lane = t & 63;
    const int w = t >> 6;           // 0..7
    const int wr = w >> 2;          // 0..1 : 64-row half
    const int wcol = w & 3;         // 0..3 : 64-col slab
    const int lrow = lane & 15;
    const int lgrp = lane >> 4;

    // staging geometry: 16KB slice = 1024 x 16B; each thread does slots t and t+512
    const int sr0 = t >> 3;                 // row of slot t       (0..63)
    const int sr1 = (t + 512) >> 3;         // row of slot t+512   (64..127)
    const int ssub = t & 7;                 // 16B chunk within 128B row

    // gather indices hoisted (same rows every step)
    int gi0d = 0, gi0s = 0, gi1d = 0, gi1s = 0;
    if (MODE == 0) {
        gi0d = dstI[base + sr0]; gi0s = srcI[base + sr0];
        gi1d = dstI[base + sr1]; gi1s = srcI[base + sr1];
    }

    auto stage = [&](int kk, unsigned char* buf) {
        if (MODE == 0) {
            int i0 = (kk < 2) ? gi0d : gi0s;
            int i1 = (kk < 2) ? gi1d : gi1s;
            const unsigned char* g0 = (const unsigned char*)x16 + (size_t)i0 * 256
                + (kk & 1) * 128 + ((ssub * 16) ^ ((sr0 & 7) << 4));
            const unsigned char* g1 = (const unsigned char*)x16 + (size_t)i1 * 256
                + (kk & 1) * 128 + ((ssub * 16) ^ ((sr1 & 7) << 4));
            gld_lds16(g0, buf + (t >> 6) * 1024);
            gld_lds16(g1, buf + 8192 + (t >> 6) * 1024);
        } else {
            gld_lds16(hhB + (size_t)(base + sr0) * 1024 + kk * 128 + ssub * 16,
                      buf + (t >> 6) * 1024);
            gld_lds16(hhB + (size_t)(base + sr1) * 1024 + kk * 128 + ssub * 16,
                      buf + 8192 + (t >> 6) * 1024);
        }
    };

    // prologue
    stage(0, lds);
    __syncthreads();

    f32x4 acc[4][4];
    const f32x4 zero = {0.f, 0.f, 0.f, 0.f};
#pragma unroll
    for (int mi = 0; mi < 4; ++mi)
#pragma unroll
        for (int ni = 0; ni < 4; ++ni) acc[mi][ni] = zero;

#pragma unroll
    for (int kk = 0; kk < 4; ++kk) {
        unsigned char* cur = lds + (kk & 1) * 16384;
        if (kk < 3) stage(kk + 1, lds + ((kk + 1) & 1) * 16384);

        // B fragments straight from L2 (16B each, pipelined by compiler)
        half8 bf[4][2];
#pragma unroll
        for (int ni = 0; ni < 4; ++ni)
#pragma unroll
            for (int kI = 0; kI < 2; ++kI)
                bf[ni][kI] = *(const half8*)(Wh + (size_t)(wcol * 64 + ni * 16 + lrow) * HF
                                             + kk * 64 + kI * 32 + lgrp * 8);
        // A fragments from LDS
        half8 af[4][2];
#pragma unroll
        for (int mi = 0; mi < 4; ++mi)
#pragma unroll
            for (int kI = 0; kI < 2; ++kI) {
                int r = wr * 64 + mi * 16 + lrow;
                af[mi][kI] = *(const half8*)&cur[r * 128 + ((kI * 64 + lgrp * 16) ^ ((r & 7) << 4))];
            }
#pragma unroll
        for (int kI = 0; kI < 2; ++kI)
#pragma unroll
            for (int mi = 0; mi < 4; ++mi)
#pragma unroll
                for (int ni = 0; ni < 4; ++ni)
                    acc[mi][ni] = __builtin_amdgcn_mfma_f32_16x16x32_f16(
                        af[mi][kI], bf[ni][kI], acc[mi][ni], 0, 0, 0);
        __syncthreads();
    }

    float bc[4];
#pragma unroll
    for (int ni = 0; ni < 4; ++ni) bc[ni] = biasArr[wcol * 64 + ni * 16 + lrow];

    if (MODE < 2) {
        // fp16 swizzled out: 2 rounds of 64 rows (32KB stage, full LDS reuse)
#pragma unroll
        for (int cc = 0; cc < 2; ++cc) {
            if (cc) __syncthreads();
            if (wr == cc) {
#pragma unroll
                for (int mi = 0; mi < 4; ++mi)
#pragma unroll
                    for (int ni = 0; ni < 4; ++ni)
#pragma unroll
                        for (int r = 0; r < 4; ++r) {
                            int lr = mi * 16 + lgrp * 4 + r;          // 0..63
                            int cg = wcol * 64 + ni * 16 + lrow;      // 0..255
                            float val = selu_f(acc[mi][ni][r] + bc[ni]);
                            int pos = (cg >> 6) * 128 + (((cg & 63) * 2) ^ ((lr & 7) << 4));
                            *(short*)&lds[lr * 512 + pos] = f2h(val);
                        }
            }
            __syncthreads();
#pragma unroll
            for (int i = 0; i < 4; ++i) {
                int f = t + i * 512;                  // 2048 x 16B = 64 rows x 32
                int row = f >> 5, ch = f & 31;
                int e = base + cc * 64 + row;
                f32x4 v = *(const f32x4*)&lds[row * 512 + ch * 16];
                *(f32x4*)(outB + (size_t)e * 1024 + ch * 16) = v;
            }
        }
    } else {
        // fp32 plain out: 4 rounds of 32 rows (32KB stage) + atomic scatter
#pragma unroll
        for (int cc = 0; cc < 4; ++cc) {
            if (cc) __syncthreads();
            if (wr == (cc >> 1)) {
#pragma unroll
                for (int m2 = 0; m2 < 2; ++m2) {
                    int mi = (cc & 1) * 2 + m2;
#pragma unroll
                    for (int ni = 0; ni < 4; ++ni)
#pragma unroll
                        for (int r = 0; r < 4; ++r) {
                            int lr = m2 * 16 + lgrp * 4 + r;          // 0..31
                            int cg = wcol * 64 + ni * 16 + lrow;
                            float val = selu_f(acc[mi][ni][r] + bc[ni]);
                            *(float*)&lds[lr * 1024 + cg * 4] = val;
                            int e = base + cc * 32 + lr;
                            atomicAdd(agg + (size_t)dstI[e] * HF + cg, val);
                        }
                }
            }
            __syncthreads();
#pragma unroll
            for (int i = 0; i < 4; ++i) {
                int f = t + i * 512;                  // 2048 x 16B = 32 rows x 64
                int row = f >> 6, ch = f & 63;
                int e = base + cc * 32 + row;
                f32x4 v = *(const f32x4*)&lds[row * 1024 + ch * 16];
                *(f32x4*)(outB + (size_t)e * 1024 + ch * 16) = v;
            }
        }
    }
}

extern "C" void kernel_launch(void* const* d_in, const int* in_sizes, int n_in,
                              void* d_out, int out_size, void* d_ws, size_t ws_size,
                              hipStream_t stream) {
    const float* x     = (const float*)d_in[0];
    const int*   ei    = (const int*)d_in[1];
    const float* W0    = (const float*)d_in[2];
    const float* b0    = (const float*)d_in[3];
    const float* g0    = (const float*)d_in[4];
    const float* beta0 = (const float*)d_in[5];
    const float* m0    = (const float*)d_in[6];
    const float* v0    = (const float*)d_in[7];
    const float* Ws    = (const float*)d_in[8];
    const float* bs    = (const float*)d_in[9];
    const float* gs    = (const float*)d_in[10];
    const float* betas = (const float*)d_in[11];
    const float* ms    = (const float*)d_in[12];
    const float* vs    = (const float*)d_in[13];

    const int Nn = in_sizes[0] / IN_F;   // 20000
    const int E  = in_sizes[1] / 2;      // 320000

    float* agg  = (float*)d_out;
    float* hptr = agg + (size_t)Nn * HF;             // h region: E slots of 1KB
    unsigned char* hhB = (unsigned char*)hptr;       // fp16 intermediates in low 512B of each slot

    // ws: Wh (384KB plain fp16) | biasArr (3KB) | cnt (80KB)
    unsigned short* Wh = (unsigned short*)d_ws;
    float* biasArr = (float*)((char*)d_ws + 3 * HF * HF * sizeof(unsigned short));
    int* cnt = (int*)((char*)d_ws + 3 * HF * HF * sizeof(unsigned short) + 3 * HF * sizeof(float));

    const int* srcI = ei;        // edge_index[0]
    const int* dstI = ei + E;    // edge_index[1]

    // x16 (10.24MB fp16) parked in the agg region (dead until after GEMM1)
    unsigned short* x16 = (unsigned short*)d_out;

    cvt_x_kernel<<<(Nn * IN_F / 4 + 255) / 256, 256, 0, stream>>>(x, x16, Nn * IN_F / 4);
    prep_kernel<<<3 * HF, HF, 0, stream>>>(W0, b0, g0, beta0, m0, v0,
                                           Ws, bs, gs, betas, ms, vs, Wh, biasArr);
    hipMemsetAsync(cnt, 0, (size_t)Nn * sizeof(int), stream);
    count_kernel<<<(E + 255) / 256, 256, 0, stream>>>(dstI, cnt, E);

    gemm_kernel<0><<<E / 128, 512, 0, stream>>>(x16, hhB, dstI, srcI,
                                                Wh, biasArr, hhB, nullptr);
    hipMemsetAsync(agg, 0, (size_t)Nn * HF * sizeof(float), stream);   // x16 dead now
    gemm_kernel<1><<<E / 128, 512, 0, stream>>>(x16, hhB, dstI, srcI,
                                                Wh + HF * HF, biasArr + HF, hhB, nullptr);
    gemm_kernel<2><<<E / 128, 512, 0, stream>>>(x16, hhB, dstI, srcI,
                                                Wh + 2 * HF * HF, biasArr + 2 * HF,
                                                (unsigned char*)hptr, agg);

    finalize_kernel<<<Nn, HF, 0, stream>>>(agg, cnt);
}